// Round 5
// baseline (387.548 us; speedup 1.0000x reference)
//
#include <hip/hip_runtime.h>
#include <hip/hip_fp16.h>

// Collapsed op: out[b,h,0,p] = dot(q[b,0,h,:], K[b,p,h,:]) * rsqrt(128),
// -inf for p >= start_pos+seqlen (no-op here: total = 8192 = S).
// Device dtypes: K,Q = float32 (fp16 upconverted by harness; round-1 NaN proved
// reading them as u16 halves decodes garbage exponents).  Output = float32
// (reference output is fp16 -> harness "else float*" branch; out_npz 1.23 MB ==
// compressed 2.1 MB f32, round-3's 6.92 error == u16 writes into f32 buffer).

#define S_LEN 8192
#define NH    8
#define DH    128
#define HPT   2      // heads per thread
#define BLK   256    // threads per block = positions per block

__global__ __launch_bounds__(BLK) void qk_decode_kernel(
    const float* __restrict__ K,   // (b, S, H, D) f32
    const float* __restrict__ Q,   // (b, 1, H, D) f32
    const int* __restrict__ sp,    // start_pos
    const int* __restrict__ sl,    // seqlen
    float* __restrict__ out)       // (b, H, 1, S) f32
{
    const int b  = blockIdx.y;
    const int h0 = blockIdx.z * HPT;
    const int s  = blockIdx.x * BLK + threadIdx.x;

    // Stage q slice (2 heads x 128 f32) in LDS; reads are wave-uniform -> broadcast.
    __shared__ float qs[HPT * DH];
    for (int i = threadIdx.x; i < HPT * DH; i += BLK)
        qs[i] = Q[((size_t)b * NH + h0) * DH + i];
    __syncthreads();

    // Each thread streams 2 contiguous 512B head-rows of position s (float4 loads;
    // every fetched line is fully consumed by the wave across the loop).
    const float4* krow = (const float4*)(K + (((size_t)b * S_LEN + s) * NH + h0) * DH);

    float acc[HPT];
#pragma unroll
    for (int h = 0; h < HPT; ++h) {
        const float4* p  = krow + h * (DH / 4);
        const float*  qp = &qs[h * DH];
        float a0 = 0.f, a1 = 0.f, a2 = 0.f, a3 = 0.f;  // 4-way ILP
#pragma unroll
        for (int c = 0; c < DH / 4; c += 4) {
            float4 v0 = p[c], v1 = p[c + 1], v2 = p[c + 2], v3 = p[c + 3];
            a0 += v0.x * qp[4*c+ 0] + v0.y * qp[4*c+ 1] + v0.z * qp[4*c+ 2] + v0.w * qp[4*c+ 3];
            a1 += v1.x * qp[4*c+ 4] + v1.y * qp[4*c+ 5] + v1.z * qp[4*c+ 6] + v1.w * qp[4*c+ 7];
            a2 += v2.x * qp[4*c+ 8] + v2.y * qp[4*c+ 9] + v2.z * qp[4*c+10] + v2.w * qp[4*c+11];
            a3 += v3.x * qp[4*c+12] + v3.y * qp[4*c+13] + v3.z * qp[4*c+14] + v3.w * qp[4*c+15];
        }
        acc[h] = (a0 + a1) + (a2 + a3);
    }

    const int total = sp[0] + sl[0];
    const float scale = 0.08838834764831845f;  // 1/sqrt(128)

#pragma unroll
    for (int h = 0; h < HPT; ++h) {
        float o;
        if (s < total) {
            // match reference: f32 dot * scale, rounded through fp16
            o = __half2float(__float2half(acc[h] * scale));
        } else {
            o = -INFINITY;
        }
        out[((size_t)b * NH + h0 + h) * S_LEN + s] = o;
    }
}

extern "C" void kernel_launch(void* const* d_in, const int* in_sizes, int n_in,
                              void* d_out, int out_size, void* d_ws, size_t ws_size,
                              hipStream_t stream) {
    const float* K  = (const float*)d_in[0];
    const float* Q  = (const float*)d_in[1];
    const int*   sp = (const int*)d_in[2];
    const int*   sl = (const int*)d_in[3];
    float* out = (float*)d_out;

    dim3 grid(S_LEN / BLK, 8 /*bsz*/, NH / HPT);
    dim3 block(BLK);
    qk_decode_kernel<<<grid, block, 0, stream>>>(K, Q, sp, sl, out);
}

// Round 8
// 364.675 us; speedup vs baseline: 1.0627x; 1.0627x over previous
//
#include <hip/hip_runtime.h>
#include <hip/hip_fp16.h>

// Collapsed op: out[b,h,0,p] = dot(q[b,0,h,:], K[b,p,h,:]) * rsqrt(128),
// -inf for p >= start_pos+seqlen (no-op here: total = 8192 = S).
// K,Q = float32 (fp16-upcast), out = float32 (fp16-rounded). PROVEN round 5.
//
// Round-5 kernel was transaction-bound: lane stride 4KB -> 64 cache lines per
// load instruction. This version: whole wave reads one position's 4KB as
// contiguous 16B/lane chunks (4 x 1KB coalesced loads), dot reduced via
// 5-level shfl_xor within 32-lane halves (masks<32 never cross halves).

#define S_LEN 8192
#define NH    8
#define DH    128
#define ROW4  (NH * DH / 4)     // 256 float4 per position
#define PPW   16                // positions per wave
#define BLK   256               // 4 waves

__global__ __launch_bounds__(BLK) void qk_decode_kernel(
    const float4* __restrict__ K4,  // (b, S, H, D/4)
    const float4* __restrict__ Q4,  // (b, 1, H, D/4)
    const int* __restrict__ sp,
    const int* __restrict__ sl,
    float* __restrict__ out)        // (b, H, 1, S) f32
{
    const int lane = threadIdx.x & 63;
    const int wid  = threadIdx.x >> 6;
    const int b    = blockIdx.y;
    const int s0   = (blockIdx.x * 4 + wid) * PPW;

    // q fragment, lane-matched to K rows: group g = heads {2g (lanes 0-31),
    // 2g+1 (lanes 32-63)}, each lane holds 4 floats at d = (lane&31)*4.
    float4 qr[4];
#pragma unroll
    for (int g = 0; g < 4; ++g)
        qr[g] = Q4[b * ROW4 + g * 64 + lane];

    const int   total   = sp[0] + sl[0];
    const float scale   = 0.08838834764831845f;  // 1/sqrt(128)
    const int   halfsel = lane >> 5;
    const bool  writer  = (lane & 31) == 0;      // lanes 0 and 32

    const float4* kbase = K4 + (size_t)b * S_LEN * ROW4;

#pragma unroll 2
    for (int ps = 0; ps < PPW; ++ps) {
        const int s = s0 + ps;
        const float4* row = kbase + (size_t)s * ROW4;

        float part[4];
#pragma unroll
        for (int g = 0; g < 4; ++g) {
            float4 v = row[g * 64 + lane];       // wave: contiguous 1KB
            part[g] = v.x * qr[g].x + v.y * qr[g].y + v.z * qr[g].z + v.w * qr[g].w;
        }

#pragma unroll
        for (int g = 0; g < 4; ++g) {
            float p = part[g];
            p += __shfl_xor(p, 1);
            p += __shfl_xor(p, 2);
            p += __shfl_xor(p, 4);
            p += __shfl_xor(p, 8);
            p += __shfl_xor(p, 16);              // half-sum in every lane of each half
            if (writer) {
                float o = (s < total)
                        ? __half2float(__float2half(p * scale))
                        : -INFINITY;
                out[((size_t)b * NH + 2 * g + halfsel) * S_LEN + s] = o;
            }
        }
    }
}

extern "C" void kernel_launch(void* const* d_in, const int* in_sizes, int n_in,
                              void* d_out, int out_size, void* d_ws, size_t ws_size,
                              hipStream_t stream) {
    const float4* K4 = (const float4*)d_in[0];
    const float4* Q4 = (const float4*)d_in[1];
    const int*    sp = (const int*)d_in[2];
    const int*    sl = (const int*)d_in[3];
    float* out = (float*)d_out;

    dim3 grid(S_LEN / (PPW * 4), 8 /*bsz*/);    // 128 x 8 = 1024 blocks, 16 waves/CU
    dim3 block(BLK);
    qk_decode_kernel<<<grid, block, 0, stream>>>(K4, Q4, sp, sl, out);
}

// Round 10
// 363.290 us; speedup vs baseline: 1.0668x; 1.0038x over previous
//
#include <hip/hip_runtime.h>
#include <hip/hip_fp16.h>

// Collapsed op: out[b,h,0,p] = dot(q[b,0,h,:], K[b,p,h,:]) * rsqrt(128),
// -inf for p >= start_pos+seqlen (no-op: total = 8192 = S).
// K,Q = float32 (fp16-upcast), out = float32 (fp16-rounded). PROVEN round 5.
//
// Round-8 ran ~115us (~2.3 TB/s): suspected HBM channel-lockstep hotspotting —
// waves streamed sequential 64KB regions offset by exact 64KB multiples, so at
// any instant all waves hit the same interleave channels. This version strides
// positions by 512 (round-robin): concurrent waves cover 2MB contiguous per
// batch -> all channels active. Only the s-mapping changed vs round 8.

#define S_LEN 8192
#define NH    8
#define DH    128
#define ROW4  (NH * DH / 4)     // 256 float4 per position
#define PPW   16                // positions per wave
#define WSTRIDE (S_LEN / PPW)   // 512: stride between a wave's positions
#define BLK   256               // 4 waves

__global__ __launch_bounds__(BLK) void qk_decode_kernel(
    const float4* __restrict__ K4,  // (b, S, H, D/4)
    const float4* __restrict__ Q4,  // (b, 1, H, D/4)
    const int* __restrict__ sp,
    const int* __restrict__ sl,
    float* __restrict__ out)        // (b, H, 1, S) f32
{
    const int lane = threadIdx.x & 63;
    const int wid  = threadIdx.x >> 6;
    const int b    = blockIdx.y;
    const int w    = blockIdx.x * 4 + wid;   // wave index within batch: [0,512)

    // q fragment, lane-matched to K rows: group g = heads {2g (lanes 0-31),
    // 2g+1 (lanes 32-63)}, each lane holds 4 floats at d = (lane&31)*4.
    float4 qr[4];
#pragma unroll
    for (int g = 0; g < 4; ++g)
        qr[g] = Q4[b * ROW4 + g * 64 + lane];

    const int   total   = sp[0] + sl[0];
    const float scale   = 0.08838834764831845f;  // 1/sqrt(128)
    const int   halfsel = lane >> 5;
    const bool  writer  = (lane & 31) == 0;      // lanes 0 and 32

    const float4* kbase = K4 + (size_t)b * S_LEN * ROW4;

#pragma unroll 2
    for (int ps = 0; ps < PPW; ++ps) {
        const int s = w + ps * WSTRIDE;          // round-robin across waves
        const float4* row = kbase + (size_t)s * ROW4;

        float part[4];
#pragma unroll
        for (int g = 0; g < 4; ++g) {
            float4 v = row[g * 64 + lane];       // wave: contiguous 1KB
            part[g] = v.x * qr[g].x + v.y * qr[g].y + v.z * qr[g].z + v.w * qr[g].w;
        }

#pragma unroll
        for (int g = 0; g < 4; ++g) {
            float p = part[g];
            p += __shfl_xor(p, 1);
            p += __shfl_xor(p, 2);
            p += __shfl_xor(p, 4);
            p += __shfl_xor(p, 8);
            p += __shfl_xor(p, 16);              // half-sum within each 32-lane half
            if (writer) {
                float o = (s < total)
                        ? __half2float(__float2half(p * scale))
                        : -INFINITY;
                out[((size_t)b * NH + 2 * g + halfsel) * S_LEN + s] = o;
            }
        }
    }
}

extern "C" void kernel_launch(void* const* d_in, const int* in_sizes, int n_in,
                              void* d_out, int out_size, void* d_ws, size_t ws_size,
                              hipStream_t stream) {
    const float4* K4 = (const float4*)d_in[0];
    const float4* Q4 = (const float4*)d_in[1];
    const int*    sp = (const int*)d_in[2];
    const int*    sl = (const int*)d_in[3];
    float* out = (float*)d_out;

    dim3 grid(S_LEN / (PPW * 4), 8 /*bsz*/);    // 128 x 8 = 1024 blocks, 16 waves/CU
    dim3 block(BLK);
    qk_decode_kernel<<<grid, block, 0, stream>>>(K4, Q4, sp, sl, out);
}